// Round 16
// baseline (302.110 us; speedup 1.0000x reference)
//
#include <hip/hip_runtime.h>
#include <hip/hip_bf16.h>
#include <hip/hip_fp16.h>
#include <stdint.h>

// Problem dims (fixed): N=64, C=192, T=64, V=25, H=6, d=32, B=N*V=1600
#define N_ 64
#define C_ 192
#define T_ 64
#define V_ 25
#define H_ 6
#define D_ 32
#define B_ 1600
#define NQ_ (3 * C_ * C_)   // 110592
#define NO_ (C_ * C_)       // 36864

typedef __attribute__((ext_vector_type(8))) short s16x8;
typedef __attribute__((ext_vector_type(4))) short s16x4;
typedef __attribute__((ext_vector_type(4))) float f32x4;

__device__ __forceinline__ unsigned short f2bf(float f) {
    union { float f; uint32_t u; } v; v.f = f;
    uint32_t r = v.u + 0x7FFFu + ((v.u >> 16) & 1u);   // RNE
    return (unsigned short)(r >> 16);
}

// ---------------------------------------------------------------------------
// Kernel 1: merged  (a) x (N,C,T,V) fp32 -> xt[(n*V+v)][t][c] bf16  [768 blk]
//                   (b) weights+rel -> bf16                          [37 blk]
// ---------------------------------------------------------------------------
__global__ __launch_bounds__(256) void k_xw(const float* __restrict__ x,
                                            const float* __restrict__ wq,
                                            const float* __restrict__ wo,
                                            const float* __restrict__ rel_emb,
                                            unsigned short* __restrict__ xt,
                                            unsigned short* __restrict__ wqb,
                                            unsigned short* __restrict__ wob,
                                            unsigned short* __restrict__ relb) {
    int bid = blockIdx.x;
    if (bid >= 768) {
        int base = (bid - 768) * 4096 + threadIdx.x;
#pragma unroll
        for (int e = 0; e < 16; ++e) {
            int i = base + e * 256;
            if (i < NQ_) wqb[i] = f2bf(wq[i]);
            else if (i < NQ_ + NO_) wob[i - NQ_] = f2bf(wo[i - NQ_]);
            else {
                int j = i - (NQ_ + NO_);          // < 4096 by construction
                int m = j >> 5;
                relb[j] = (m < 127) ? f2bf(rel_emb[j]) : (unsigned short)0;
            }
        }
        return;
    }
    int virt = (bid & 7) * 96 + (bid >> 3);
    int n = virt / 12, r = virt % 12, cg = r >> 1, ih = r & 1;
    __shared__ unsigned short tile[800][40];   // 64000 B
    int tid = threadIdx.x;
    {
        int cc = tid >> 3, part = tid & 7;     // cc 0..31, 100 elems each
        const float4* src = (const float4*)(x + ((size_t)n * C_ + cg * 32 + cc) * 1600
                                              + ih * 800 + part * 100);
#pragma unroll
        for (int u = 0; u < 25; ++u) {
            float4 f = src[u];
            int i = part * 100 + u * 4;
            tile[i + 0][cc] = f2bf(f.x);
            tile[i + 1][cc] = f2bf(f.y);
            tile[i + 2][cc] = f2bf(f.z);
            tile[i + 3][cc] = f2bf(f.w);
        }
    }
    __syncthreads();
    for (int i = tid; i < 800; i += 256) {
        int gi = ih * 800 + i;
        int t = (gi * 5243) >> 17;             // gi/25 (exact for gi<1600)
        int v = gi - t * 25;
        unsigned short* dst = xt + (((size_t)(n * V_ + v) * T_) + t) * C_ + cg * 32;
        const s16x8* srow = (const s16x8*)&tile[i][0];
        ((s16x8*)dst)[0] = srow[0];
        ((s16x8*)dst)[1] = srow[1];
        ((s16x8*)dst)[2] = srow[2];
        ((s16x8*)dst)[3] = srow[3];
    }
}

// ---------------------------------------------------------------------------
// Kernel 2: FUSED (b, j): 3-phase QKV slab GEMM + 2 wave-local attention
// passes.  v3: NO xts staging (B-frags direct from L2-hot xt), ao aliases qt.
// LDS 38,912 B -> 4 blocks/CU.  2 barriers.
//   U+0     : relw [4][16][88] (half bits) ∪ wls [4][16][72]  (5632)
//   U+5632  : qt [2][64][36]  ∪ ao [2][64][36] (pass r overwrites the strip
//             whose afq it already consumed; other wave's strips disjoint)
//   U+10240 : kt [2][64][36]
//   U+14848 : vsm [2][32][72]
// Math bit-identical to R15 -> absmax 0.078125.
// ---------------------------------------------------------------------------
__global__ __launch_bounds__(256, 4) void k_qa(const unsigned short* __restrict__ Wb,
                                               const float* __restrict__ bqkv,
                                               const unsigned short* __restrict__ xt,
                                               const unsigned short* __restrict__ relb,
                                               unsigned short* __restrict__ aT) {
    int virt = (blockIdx.x & 7) * 600 + (blockIdx.x >> 3);   // 4800 = 8*600
    int b = virt / 3, j = virt % 3;

    __shared__ __align__(16) unsigned short U[19456];        // 38,912 B
    unsigned short* relw = U;            // wave*1408 + row*88 + col (half bits)
    unsigned short* wls  = U;            // wave*1408 + row*72 + col (aliases relw)
    unsigned short* qt   = U + 5632;     // [2][64][36]; ao aliases this
    unsigned short* ao   = U + 5632;
    unsigned short* kt   = U + 10240;    // [2][64][36]
    unsigned short* vsm  = U + 14848;    // [2][32][72]

    int tid = threadIdx.x;
    int wave = tid >> 6, lane = tid & 63;
    int lr = lane & 15, lg = lane >> 4;
    int w1 = wave & 1;
    int hh = wave >> 1;                  // local head of this wave
    int dh = w1 * 16;                    // d-base within head

    const unsigned short* xb = xt + (size_t)b * T_ * C_;

    // ---- 3 GEMM phases (q,k,v slab j); B-frags direct from global ----
#pragma unroll
    for (int p = 0; p < 3; ++p) {
        int mo = p * 3 + j;
        const unsigned short* arow =
            Wb + (size_t)(mo * 64 + wave * 16 + lr) * C_ + lg * 8;
        f32x4 acc[4];
#pragma unroll
        for (int nt = 0; nt < 4; ++nt) acc[nt] = (f32x4){0.f, 0.f, 0.f, 0.f};
#pragma unroll
        for (int k0 = 0; k0 < C_; k0 += 32) {
            s16x8 a = *(const s16x8*)(arow + k0);
#pragma unroll
            for (int nt = 0; nt < 4; ++nt) {
                s16x8 bfv = *(const s16x8*)(xb + (size_t)(nt * 16 + lr) * C_ + k0 + lg * 8);
                acc[nt] = __builtin_amdgcn_mfma_f32_16x16x32_bf16(a, bfv, acc[nt], 0, 0, 0);
            }
        }
        if (p < 2) {
            unsigned short* dst = (p == 0 ? qt : kt);
#pragma unroll
            for (int nt = 0; nt < 4; ++nt) {
                s16x4 pk;
#pragma unroll
                for (int r2 = 0; r2 < 4; ++r2)
                    pk[r2] = (short)f2bf(acc[nt][r2] +
                                         bqkv[mo * 64 + wave * 16 + lg * 4 + r2]);
                *(s16x4*)&dst[hh * 2304 + (nt * 16 + lr) * 36 + dh + lg * 4] = pk;
            }
        } else {
#pragma unroll
            for (int nt = 0; nt < 4; ++nt)
#pragma unroll
                for (int r2 = 0; r2 < 4; ++r2) {
                    int d = dh + lg * 4 + r2;
                    vsm[hh * 2304 + d * 72 + nt * 16 + lr] =
                        f2bf(acc[nt][r2] + bqkv[mo * 64 + wave * 16 + lg * 4 + r2]);
                }
        }
    }
    // rel window union for both passes (6 tiles; pass r uses rfr6[1-r+ti]);
    // issued before the barrier so latency hides under the wait
    s16x8 rfr6[6];
#pragma unroll
    for (int ti = 0; ti < 6; ++ti) {
        int m = (2 - 2 * w1 + ti) * 16 + lr;
        rfr6[ti] = *(const s16x8*)(relb + m * 32 + lg * 8);
    }
    __syncthreads();                           // b2: qt/kt/vsm complete

    // ---- attention: 2 wave-local passes ----
#pragma unroll
    for (int r = 0; r < 2; ++r) {
        int strip = 2 * w1 + r;
        int t0s = strip * 16;

        int qoff = hh * 2304 + (t0s + lr) * 36 + lg * 8;
        s16x4 qlo = *(const s16x4*)&qt[qoff];
        s16x4 qhi = *(const s16x4*)&qt[qoff + 4];
        s16x8 afq = __builtin_shufflevector(qlo, qhi, 0, 1, 2, 3, 4, 5, 6, 7);

        f32x4 accS[4];
#pragma unroll
        for (int nt = 0; nt < 4; ++nt) {
            int koff = hh * 2304 + (nt * 16 + lr) * 36 + lg * 8;
            s16x4 klo = *(const s16x4*)&kt[koff];
            s16x4 khi = *(const s16x4*)&kt[koff + 4];
            s16x8 bk = __builtin_shufflevector(klo, khi, 0, 1, 2, 3, 4, 5, 6, 7);
            f32x4 z = (f32x4){0.f, 0.f, 0.f, 0.f};
            accS[nt] = __builtin_amdgcn_mfma_f32_16x16x32_bf16(afq, bk, z, 0, 0, 0);
        }
#pragma unroll
        for (int ti = 0; ti < 5; ++ti) {
            f32x4 z = (f32x4){0.f, 0.f, 0.f, 0.f};
            f32x4 rr = __builtin_amdgcn_mfma_f32_16x16x32_bf16(afq, rfr6[1 - r + ti], z, 0, 0, 0);
#pragma unroll
            for (int r2 = 0; r2 < 4; ++r2)
                relw[wave * 1408 + (lg * 4 + r2) * 88 + ti * 16 + lr] =
                    __half_as_ushort(__float2half(rr[r2]));
        }
        // softmax (wave-local; relw wave-private)
        float vals[4][4], mx[4], inv[4];
#pragma unroll
        for (int r2 = 0; r2 < 4; ++r2) {
            int row = lg * 4 + r2;
            float m0 = -1e30f;
#pragma unroll
            for (int nt = 0; nt < 4; ++nt) {
                int s = nt * 16 + lr;
                float v = accS[nt][r2] + __half2float(__ushort_as_half(
                              relw[wave * 1408 + row * 88 + (s - row + 15)]));
                vals[nt][r2] = v;
                m0 = fmaxf(m0, v);
            }
            m0 = fmaxf(m0, __shfl_xor(m0, 1));
            m0 = fmaxf(m0, __shfl_xor(m0, 2));
            m0 = fmaxf(m0, __shfl_xor(m0, 4));
            m0 = fmaxf(m0, __shfl_xor(m0, 8));
            mx[r2] = m0;
        }
#pragma unroll
        for (int r2 = 0; r2 < 4; ++r2) {
            float s0 = 0.f;
#pragma unroll
            for (int nt = 0; nt < 4; ++nt) {
                float e = __expf(vals[nt][r2] - mx[r2]);
                vals[nt][r2] = e;
                s0 += e;
            }
            s0 += __shfl_xor(s0, 1);
            s0 += __shfl_xor(s0, 2);
            s0 += __shfl_xor(s0, 4);
            s0 += __shfl_xor(s0, 8);
            inv[r2] = 1.0f / s0;
        }
        // wls writes alias relw: all relw reads above complete (same wave,
        // program order; DS ops wave-ordered; same-type may-alias)
#pragma unroll
        for (int r2 = 0; r2 < 4; ++r2) {
            int row = lg * 4 + r2;
#pragma unroll
            for (int nt = 0; nt < 4; ++nt)
                wls[wave * 1408 + row * 72 + nt * 16 + lr] =
                    f2bf(vals[nt][r2] * inv[r2]);
        }
        // PV (wls wave-private)
        f32x4 accO[2];
        accO[0] = (f32x4){0.f, 0.f, 0.f, 0.f};
        accO[1] = (f32x4){0.f, 0.f, 0.f, 0.f};
#pragma unroll
        for (int ks = 0; ks < 2; ++ks) {
            s16x8 pa = *(const s16x8*)&wls[wave * 1408 + lr * 72 + ks * 32 + lg * 8];
#pragma unroll
            for (int nt = 0; nt < 2; ++nt) {
                s16x8 bv = *(const s16x8*)&vsm[hh * 2304 + (nt * 16 + lr) * 72 +
                                               ks * 32 + lg * 8];
                accO[nt] = __builtin_amdgcn_mfma_f32_16x16x32_bf16(pa, bv, accO[nt], 0, 0, 0);
            }
        }
        // ao overwrites qt[strip rows] — this wave's afq for the strip is
        // consumed; other wave of head hh owns disjoint strips
#pragma unroll
        for (int nt = 0; nt < 2; ++nt)
#pragma unroll
            for (int r2 = 0; r2 < 4; ++r2)
                ao[hh * 2304 + (t0s + lg * 4 + r2) * 36 + nt * 16 + lr] =
                    f2bf(accO[nt][r2]);
    }
    __syncthreads();                           // b3

    // scrambled write for both heads: aT[b][tout][(2j+hh)*32+qr] = ao[hh][tAo][dA]
    unsigned short* dstb = aT + (size_t)b * T_ * C_ + 2 * j * D_;
#pragma unroll
    for (int it = 0; it < 16; ++it) {
        int idx = it * 256 + tid;              // 0..4095
        int hh2 = idx >> 11;
        int e = idx & 2047;
        int qr = e & 31, tout = e >> 5;
        int ii = tout & 31;
        int jj = 2 * qr + (tout >> 5);
        int tAo = 2 * ii + (jj >> 5);
        int dA = jj & 31;
        dstb[(size_t)tout * C_ + hh2 * D_ + qr] = ao[hh2 * 2304 + tAo * 36 + dA];
    }
}

// ---------------------------------------------------------------------------
// Kernel 3: out GEMM (bf16 MFMA), writes final (N,C,T,V) fp32. XCD-swizzled.
// (round-9 scatter epilogue)
// ---------------------------------------------------------------------------
__global__ __launch_bounds__(256) void k_out(const unsigned short* __restrict__ Wb,
                                             const float* __restrict__ bias,
                                             const unsigned short* __restrict__ aT,
                                             float* __restrict__ out) {
    int virt = (blockIdx.x & 7) * (768 / 8) + (blockIdx.x >> 3);
    int n = virt / 12, r = virt % 12, mo = r >> 2, tc = r & 3;
    __shared__ unsigned short Bs[400][40];     // [col][k], 32KB
    int tid = threadIdx.x;
    int wave = tid >> 6, lane = tid & 63;
    int lr = lane & 15, lg = lane >> 4;

    f32x4 acc[25];
#pragma unroll
    for (int j = 0; j < 25; ++j) acc[j] = (f32x4){0.f, 0.f, 0.f, 0.f};

    const unsigned short* arow = Wb + (size_t)(mo * 64 + wave * 16 + lr) * C_ + lg * 8;

    for (int k0 = 0; k0 < C_; k0 += 32) {
        __syncthreads();
        for (int col = tid; col < 400; col += 256) {
            int tl = (col * 41) >> 10;         // col/25 (exact for col<624)
            int v = col - tl * 25;
            const s16x8* src = (const s16x8*)(aT +
                ((size_t)(n * V_ + v) * T_ + tc * 16 + tl) * C_ + k0);
            s16x8* dst = (s16x8*)&Bs[col][0];
            dst[0] = src[0]; dst[1] = src[1]; dst[2] = src[2]; dst[3] = src[3];
        }
        __syncthreads();
        s16x8 a = *(const s16x8*)(arow + k0);
#pragma unroll
        for (int j = 0; j < 25; ++j) {
            s16x8 bf = *(const s16x8*)&Bs[j * 16 + lr][lg * 8];
            acc[j] = __builtin_amdgcn_mfma_f32_16x16x32_bf16(a, bf, acc[j], 0, 0, 0);
        }
    }
#pragma unroll
    for (int j = 0; j < 25; ++j) {
        int c = j * 16 + lr;
        int tl = (c * 41) >> 10;
        int v = c - tl * 25;
        int t = tc * 16 + tl;
#pragma unroll
        for (int r2 = 0; r2 < 4; ++r2) {
            int o = mo * 64 + wave * 16 + lg * 4 + r2;
            out[(((size_t)n * C_ + o) * T_ + t) * V_ + v] = acc[j][r2] + bias[o];
        }
    }
}

// ---------------------------------------------------------------------------
extern "C" void kernel_launch(void* const* d_in, const int* in_sizes, int n_in,
                              void* d_out, int out_size, void* d_ws, size_t ws_size,
                              hipStream_t stream) {
    const float* x       = (const float*)d_in[0];
    const float* w_qkv   = (const float*)d_in[1];
    const float* b_qkv   = (const float*)d_in[2];
    const float* w_out   = (const float*)d_in[3];
    const float* b_out   = (const float*)d_in[4];
    const float* rel_emb = (const float*)d_in[5];
    float* out = (float*)d_out;

    // workspace (ushorts): xt | aT | wqb | wob | relb
    const size_t PLANE = (size_t)B_ * T_ * C_;   // 19,660,800
    unsigned short* xt   = (unsigned short*)d_ws;
    unsigned short* aTb  = xt + PLANE;
    unsigned short* wqb  = aTb + PLANE;
    unsigned short* wob  = wqb + (size_t)NQ_;
    unsigned short* relb = wob + (size_t)NO_;

    k_xw<<<805, 256, 0, stream>>>(x, w_qkv, w_out, rel_emb, xt, wqb, wob, relb);
    k_qa<<<4800, 256, 0, stream>>>(wqb, b_qkv, xt, relb, aTb);
    k_out<<<768, 256, 0, stream>>>(wob, b_out, aTb, out);
}

// Round 17
// 148.626 us; speedup vs baseline: 2.0327x; 2.0327x over previous
//
#include <hip/hip_runtime.h>
#include <hip/hip_bf16.h>
#include <hip/hip_fp16.h>
#include <stdint.h>

// Problem dims (fixed): N=64, C=192, T=64, V=25, H=6, d=32, B=N*V=1600
#define N_ 64
#define C_ 192
#define T_ 64
#define V_ 25
#define H_ 6
#define D_ 32
#define B_ 1600
#define NQ_ (3 * C_ * C_)   // 110592
#define NO_ (C_ * C_)       // 36864

typedef __attribute__((ext_vector_type(8))) short s16x8;
typedef __attribute__((ext_vector_type(4))) short s16x4;
typedef __attribute__((ext_vector_type(4))) float f32x4;

__device__ __forceinline__ unsigned short f2bf(float f) {
    union { float f; uint32_t u; } v; v.f = f;
    uint32_t r = v.u + 0x7FFFu + ((v.u >> 16) & 1u);   // RNE
    return (unsigned short)(r >> 16);
}

// ---------------------------------------------------------------------------
// Kernel 1: merged  (a) x (N,C,T,V) fp32 -> xt[(n*V+v)][t][c] bf16  [768 blk]
//                   (b) weights+rel -> bf16                          [37 blk]
// ---------------------------------------------------------------------------
__global__ __launch_bounds__(256) void k_xw(const float* __restrict__ x,
                                            const float* __restrict__ wq,
                                            const float* __restrict__ wo,
                                            const float* __restrict__ rel_emb,
                                            unsigned short* __restrict__ xt,
                                            unsigned short* __restrict__ wqb,
                                            unsigned short* __restrict__ wob,
                                            unsigned short* __restrict__ relb) {
    int bid = blockIdx.x;
    if (bid >= 768) {
        int base = (bid - 768) * 4096 + threadIdx.x;
#pragma unroll
        for (int e = 0; e < 16; ++e) {
            int i = base + e * 256;
            if (i < NQ_) wqb[i] = f2bf(wq[i]);
            else if (i < NQ_ + NO_) wob[i - NQ_] = f2bf(wo[i - NQ_]);
            else {
                int j = i - (NQ_ + NO_);          // < 4096 by construction
                int m = j >> 5;
                relb[j] = (m < 127) ? f2bf(rel_emb[j]) : (unsigned short)0;
            }
        }
        return;
    }
    int virt = (bid & 7) * 96 + (bid >> 3);
    int n = virt / 12, r = virt % 12, cg = r >> 1, ih = r & 1;
    __shared__ unsigned short tile[800][40];   // 64000 B
    int tid = threadIdx.x;
    {
        int cc = tid >> 3, part = tid & 7;     // cc 0..31, 100 elems each
        const float4* src = (const float4*)(x + ((size_t)n * C_ + cg * 32 + cc) * 1600
                                              + ih * 800 + part * 100);
#pragma unroll
        for (int u = 0; u < 25; ++u) {
            float4 f = src[u];
            int i = part * 100 + u * 4;
            tile[i + 0][cc] = f2bf(f.x);
            tile[i + 1][cc] = f2bf(f.y);
            tile[i + 2][cc] = f2bf(f.z);
            tile[i + 3][cc] = f2bf(f.w);
        }
    }
    __syncthreads();
    for (int i = tid; i < 800; i += 256) {
        int gi = ih * 800 + i;
        int t = (gi * 5243) >> 17;             // gi/25 (exact for gi<1600)
        int v = gi - t * 25;
        unsigned short* dst = xt + (((size_t)(n * V_ + v) * T_) + t) * C_ + cg * 32;
        const s16x8* srow = (const s16x8*)&tile[i][0];
        ((s16x8*)dst)[0] = srow[0];
        ((s16x8*)dst)[1] = srow[1];
        ((s16x8*)dst)[2] = srow[2];
        ((s16x8*)dst)[3] = srow[3];
    }
}

// ---------------------------------------------------------------------------
// Kernel 2: FUSED (b, j): 3-phase QKV slab GEMM + 2 wave-local attention
// passes.  v4: xts staged in TWO k-halves [64][104] (phase accumulators kept
// alive across the restage) -> LDS 40,960 B -> 4 blocks/CU, with LDS-staged
// B-operands intact (R16's global-B variant was latency-bound).
//   U+0     : xts [64][104] (GEMM halves) — after GEMM: relw [4][16][88]
//             (half bits) ∪ wls [4][16][72]
//   U+6656  : qt [2][64][36] ∪ ao (pass r overwrites only the strip whose
//             afq it already consumed; strips wave-disjoint)
//   U+11264 : kt [2][64][36]
//   U+15872 : vsm [2][32][72]
// Math bit-identical to R15 (same per-phase k accumulation order 0..160).
// ---------------------------------------------------------------------------
__global__ __launch_bounds__(256, 4) void k_qa(const unsigned short* __restrict__ Wb,
                                               const float* __restrict__ bqkv,
                                               const unsigned short* __restrict__ xt,
                                               const unsigned short* __restrict__ relb,
                                               unsigned short* __restrict__ aT) {
    int virt = (blockIdx.x & 7) * 600 + (blockIdx.x >> 3);   // 4800 = 8*600
    int b = virt / 3, j = virt % 3;

    __shared__ __align__(16) unsigned short U[20480];        // 40,960 B
    unsigned short* xts  = U;            // [64][104] per k-half
    unsigned short* relw = U;            // wave*1408 + row*88 + col (half bits)
    unsigned short* wls  = U;            // wave*1408 + row*72 + col (aliases relw)
    unsigned short* qt   = U + 6656;     // [2][64][36]; ao aliases this
    unsigned short* ao   = U + 6656;
    unsigned short* kt   = U + 11264;    // [2][64][36]
    unsigned short* vsm  = U + 15872;    // [2][32][72]

    int tid = threadIdx.x;
    int wave = tid >> 6, lane = tid & 63;
    int lr = lane & 15, lg = lane >> 4;
    int w1 = wave & 1;
    int hh = wave >> 1;                  // local head of this wave
    int dh = w1 * 16;                    // d-base within head

    const unsigned short* xb = xt + (size_t)b * T_ * C_;

    f32x4 acc3[3][4];
#pragma unroll
    for (int p = 0; p < 3; ++p)
#pragma unroll
        for (int nt = 0; nt < 4; ++nt) acc3[p][nt] = (f32x4){0.f, 0.f, 0.f, 0.f};

    // ---- GEMM over two k-halves; acc3 persists across the restage ----
#pragma unroll
    for (int hch = 0; hch < 2; ++hch) {
        // stage xts half: rows t, 96 ushorts each (3 x s16x8 per thread)
        {
            int t = tid >> 2, q4 = tid & 3;
            const s16x8* src = (const s16x8*)(xb + (size_t)t * C_ + hch * 96 + q4 * 24);
            s16x8* dst = (s16x8*)&xts[t * 104 + q4 * 24];
            dst[0] = src[0]; dst[1] = src[1]; dst[2] = src[2];
        }
        __syncthreads();                       // half staged
#pragma unroll
        for (int p = 0; p < 3; ++p) {
            int mo = p * 3 + j;
            const unsigned short* arow =
                Wb + (size_t)(mo * 64 + wave * 16 + lr) * C_ + hch * 96 + lg * 8;
#pragma unroll
            for (int ks = 0; ks < 3; ++ks) {
                int k0 = ks * 32;
                s16x8 a = *(const s16x8*)(arow + k0);
#pragma unroll
                for (int nt = 0; nt < 4; ++nt) {
                    s16x8 bfv = *(const s16x8*)&xts[(nt * 16 + lr) * 104 + k0 + lg * 8];
                    acc3[p][nt] = __builtin_amdgcn_mfma_f32_16x16x32_bf16(a, bfv, acc3[p][nt], 0, 0, 0);
                }
            }
        }
        __syncthreads();                       // half reads done (safe restage/alias)
    }

    // ---- epilogues: qt / kt / vsm ----
#pragma unroll
    for (int p = 0; p < 3; ++p) {
        int mo = p * 3 + j;
        if (p < 2) {
            unsigned short* dst = (p == 0 ? qt : kt);
#pragma unroll
            for (int nt = 0; nt < 4; ++nt) {
                s16x4 pk;
#pragma unroll
                for (int r2 = 0; r2 < 4; ++r2)
                    pk[r2] = (short)f2bf(acc3[p][nt][r2] +
                                         bqkv[mo * 64 + wave * 16 + lg * 4 + r2]);
                *(s16x4*)&dst[hh * 2304 + (nt * 16 + lr) * 36 + dh + lg * 4] = pk;
            }
        } else {
#pragma unroll
            for (int nt = 0; nt < 4; ++nt)
#pragma unroll
                for (int r2 = 0; r2 < 4; ++r2) {
                    int d = dh + lg * 4 + r2;
                    vsm[hh * 2304 + d * 72 + nt * 16 + lr] =
                        f2bf(acc3[p][nt][r2] + bqkv[mo * 64 + wave * 16 + lg * 4 + r2]);
                }
        }
    }
    // rel window union for both passes (6 tiles; pass r uses rfr6[1-r+ti]);
    // issued before the barrier so latency hides under the wait
    s16x8 rfr6[6];
#pragma unroll
    for (int ti = 0; ti < 6; ++ti) {
        int m = (2 - 2 * w1 + ti) * 16 + lr;
        rfr6[ti] = *(const s16x8*)(relb + m * 32 + lg * 8);
    }
    __syncthreads();                           // qt/kt/vsm complete; xts dead

    // ---- attention: 2 wave-local passes (R15 body) ----
#pragma unroll
    for (int r = 0; r < 2; ++r) {
        int strip = 2 * w1 + r;
        int t0s = strip * 16;

        int qoff = hh * 2304 + (t0s + lr) * 36 + lg * 8;
        s16x4 qlo = *(const s16x4*)&qt[qoff];
        s16x4 qhi = *(const s16x4*)&qt[qoff + 4];
        s16x8 afq = __builtin_shufflevector(qlo, qhi, 0, 1, 2, 3, 4, 5, 6, 7);

        f32x4 accS[4];
#pragma unroll
        for (int nt = 0; nt < 4; ++nt) {
            int koff = hh * 2304 + (nt * 16 + lr) * 36 + lg * 8;
            s16x4 klo = *(const s16x4*)&kt[koff];
            s16x4 khi = *(const s16x4*)&kt[koff + 4];
            s16x8 bk = __builtin_shufflevector(klo, khi, 0, 1, 2, 3, 4, 5, 6, 7);
            f32x4 z = (f32x4){0.f, 0.f, 0.f, 0.f};
            accS[nt] = __builtin_amdgcn_mfma_f32_16x16x32_bf16(afq, bk, z, 0, 0, 0);
        }
#pragma unroll
        for (int ti = 0; ti < 5; ++ti) {
            f32x4 z = (f32x4){0.f, 0.f, 0.f, 0.f};
            f32x4 rr = __builtin_amdgcn_mfma_f32_16x16x32_bf16(afq, rfr6[1 - r + ti], z, 0, 0, 0);
#pragma unroll
            for (int r2 = 0; r2 < 4; ++r2)
                relw[wave * 1408 + (lg * 4 + r2) * 88 + ti * 16 + lr] =
                    __half_as_ushort(__float2half(rr[r2]));
        }
        // softmax (wave-local; relw wave-private)
        float vals[4][4], mx[4], inv[4];
#pragma unroll
        for (int r2 = 0; r2 < 4; ++r2) {
            int row = lg * 4 + r2;
            float m0 = -1e30f;
#pragma unroll
            for (int nt = 0; nt < 4; ++nt) {
                int s = nt * 16 + lr;
                float v = accS[nt][r2] + __half2float(__ushort_as_half(
                              relw[wave * 1408 + row * 88 + (s - row + 15)]));
                vals[nt][r2] = v;
                m0 = fmaxf(m0, v);
            }
            m0 = fmaxf(m0, __shfl_xor(m0, 1));
            m0 = fmaxf(m0, __shfl_xor(m0, 2));
            m0 = fmaxf(m0, __shfl_xor(m0, 4));
            m0 = fmaxf(m0, __shfl_xor(m0, 8));
            mx[r2] = m0;
        }
#pragma unroll
        for (int r2 = 0; r2 < 4; ++r2) {
            float s0 = 0.f;
#pragma unroll
            for (int nt = 0; nt < 4; ++nt) {
                float e = __expf(vals[nt][r2] - mx[r2]);
                vals[nt][r2] = e;
                s0 += e;
            }
            s0 += __shfl_xor(s0, 1);
            s0 += __shfl_xor(s0, 2);
            s0 += __shfl_xor(s0, 4);
            s0 += __shfl_xor(s0, 8);
            inv[r2] = 1.0f / s0;
        }
        // wls writes alias relw: all relw reads above complete (same wave,
        // program order; DS ops wave-ordered; same-type may-alias)
#pragma unroll
        for (int r2 = 0; r2 < 4; ++r2) {
            int row = lg * 4 + r2;
#pragma unroll
            for (int nt = 0; nt < 4; ++nt)
                wls[wave * 1408 + row * 72 + nt * 16 + lr] =
                    f2bf(vals[nt][r2] * inv[r2]);
        }
        // PV (wls wave-private)
        f32x4 accO[2];
        accO[0] = (f32x4){0.f, 0.f, 0.f, 0.f};
        accO[1] = (f32x4){0.f, 0.f, 0.f, 0.f};
#pragma unroll
        for (int ks = 0; ks < 2; ++ks) {
            s16x8 pa = *(const s16x8*)&wls[wave * 1408 + lr * 72 + ks * 32 + lg * 8];
#pragma unroll
            for (int nt = 0; nt < 2; ++nt) {
                s16x8 bv = *(const s16x8*)&vsm[hh * 2304 + (nt * 16 + lr) * 72 +
                                               ks * 32 + lg * 8];
                accO[nt] = __builtin_amdgcn_mfma_f32_16x16x32_bf16(pa, bv, accO[nt], 0, 0, 0);
            }
        }
        // ao overwrites qt[strip rows] — afq for this strip already consumed;
        // other wave of head hh owns disjoint strips
#pragma unroll
        for (int nt = 0; nt < 2; ++nt)
#pragma unroll
            for (int r2 = 0; r2 < 4; ++r2)
                ao[hh * 2304 + (t0s + lg * 4 + r2) * 36 + nt * 16 + lr] =
                    f2bf(accO[nt][r2]);
    }
    __syncthreads();                           // ao complete

    // scrambled write for both heads: aT[b][tout][(2j+hh)*32+qr] = ao[hh][tAo][dA]
    unsigned short* dstb = aT + (size_t)b * T_ * C_ + 2 * j * D_;
#pragma unroll
    for (int it = 0; it < 16; ++it) {
        int idx = it * 256 + tid;              // 0..4095
        int hh2 = idx >> 11;
        int e = idx & 2047;
        int qr = e & 31, tout = e >> 5;
        int ii = tout & 31;
        int jj = 2 * qr + (tout >> 5);
        int tAo = 2 * ii + (jj >> 5);
        int dA = jj & 31;
        dstb[(size_t)tout * C_ + hh2 * D_ + qr] = ao[hh2 * 2304 + tAo * 36 + dA];
    }
}

// ---------------------------------------------------------------------------
// Kernel 3: out GEMM (bf16 MFMA), writes final (N,C,T,V) fp32. XCD-swizzled.
// (round-9 scatter epilogue)
// ---------------------------------------------------------------------------
__global__ __launch_bounds__(256) void k_out(const unsigned short* __restrict__ Wb,
                                             const float* __restrict__ bias,
                                             const unsigned short* __restrict__ aT,
                                             float* __restrict__ out) {
    int virt = (blockIdx.x & 7) * (768 / 8) + (blockIdx.x >> 3);
    int n = virt / 12, r = virt % 12, mo = r >> 2, tc = r & 3;
    __shared__ unsigned short Bs[400][40];     // [col][k], 32KB
    int tid = threadIdx.x;
    int wave = tid >> 6, lane = tid & 63;
    int lr = lane & 15, lg = lane >> 4;

    f32x4 acc[25];
#pragma unroll
    for (int j = 0; j < 25; ++j) acc[j] = (f32x4){0.f, 0.f, 0.f, 0.f};

    const unsigned short* arow = Wb + (size_t)(mo * 64 + wave * 16 + lr) * C_ + lg * 8;

    for (int k0 = 0; k0 < C_; k0 += 32) {
        __syncthreads();
        for (int col = tid; col < 400; col += 256) {
            int tl = (col * 41) >> 10;         // col/25 (exact for col<624)
            int v = col - tl * 25;
            const s16x8* src = (const s16x8*)(aT +
                ((size_t)(n * V_ + v) * T_ + tc * 16 + tl) * C_ + k0);
            s16x8* dst = (s16x8*)&Bs[col][0];
            dst[0] = src[0]; dst[1] = src[1]; dst[2] = src[2]; dst[3] = src[3];
        }
        __syncthreads();
        s16x8 a = *(const s16x8*)(arow + k0);
#pragma unroll
        for (int j = 0; j < 25; ++j) {
            s16x8 bf = *(const s16x8*)&Bs[j * 16 + lr][lg * 8];
            acc[j] = __builtin_amdgcn_mfma_f32_16x16x32_bf16(a, bf, acc[j], 0, 0, 0);
        }
    }
#pragma unroll
    for (int j = 0; j < 25; ++j) {
        int c = j * 16 + lr;
        int tl = (c * 41) >> 10;
        int v = c - tl * 25;
        int t = tc * 16 + tl;
#pragma unroll
        for (int r2 = 0; r2 < 4; ++r2) {
            int o = mo * 64 + wave * 16 + lg * 4 + r2;
            out[(((size_t)n * C_ + o) * T_ + t) * V_ + v] = acc[j][r2] + bias[o];
        }
    }
}

// ---------------------------------------------------------------------------
extern "C" void kernel_launch(void* const* d_in, const int* in_sizes, int n_in,
                              void* d_out, int out_size, void* d_ws, size_t ws_size,
                              hipStream_t stream) {
    const float* x       = (const float*)d_in[0];
    const float* w_qkv   = (const float*)d_in[1];
    const float* b_qkv   = (const float*)d_in[2];
    const float* w_out   = (const float*)d_in[3];
    const float* b_out   = (const float*)d_in[4];
    const float* rel_emb = (const float*)d_in[5];
    float* out = (float*)d_out;

    // workspace (ushorts): xt | aT | wqb | wob | relb
    const size_t PLANE = (size_t)B_ * T_ * C_;   // 19,660,800
    unsigned short* xt   = (unsigned short*)d_ws;
    unsigned short* aTb  = xt + PLANE;
    unsigned short* wqb  = aTb + PLANE;
    unsigned short* wob  = wqb + (size_t)NQ_;
    unsigned short* relb = wob + (size_t)NO_;

    k_xw<<<805, 256, 0, stream>>>(x, w_qkv, w_out, rel_emb, xt, wqb, wob, relb);
    k_qa<<<4800, 256, 0, stream>>>(wqb, b_qkv, xt, relb, aTb);
    k_out<<<768, 256, 0, stream>>>(wob, b_out, aTb, out);
}

// Round 18
// 148.167 us; speedup vs baseline: 2.0390x; 1.0031x over previous
//
#include <hip/hip_runtime.h>
#include <hip/hip_bf16.h>
#include <hip/hip_fp16.h>
#include <stdint.h>

// Problem dims (fixed): N=64, C=192, T=64, V=25, H=6, d=32, B=N*V=1600
#define N_ 64
#define C_ 192
#define T_ 64
#define V_ 25
#define H_ 6
#define D_ 32
#define B_ 1600
#define NQ_ (3 * C_ * C_)   // 110592
#define NO_ (C_ * C_)       // 36864

typedef __attribute__((ext_vector_type(8))) short s16x8;
typedef __attribute__((ext_vector_type(4))) short s16x4;
typedef __attribute__((ext_vector_type(4))) float f32x4;

__device__ __forceinline__ unsigned short f2bf(float f) {
    union { float f; uint32_t u; } v; v.f = f;
    uint32_t r = v.u + 0x7FFFu + ((v.u >> 16) & 1u);   // RNE
    return (unsigned short)(r >> 16);
}

// ---------------------------------------------------------------------------
// Kernel 1: merged  (a) x (N,C,T,V) fp32 -> xt[(n*V+v)][t][c] bf16  [768 blk]
//                   (b) weights+rel -> bf16                          [37 blk]
// ---------------------------------------------------------------------------
__global__ __launch_bounds__(256) void k_xw(const float* __restrict__ x,
                                            const float* __restrict__ wq,
                                            const float* __restrict__ wo,
                                            const float* __restrict__ rel_emb,
                                            unsigned short* __restrict__ xt,
                                            unsigned short* __restrict__ wqb,
                                            unsigned short* __restrict__ wob,
                                            unsigned short* __restrict__ relb) {
    int bid = blockIdx.x;
    if (bid >= 768) {
        int base = (bid - 768) * 4096 + threadIdx.x;
#pragma unroll
        for (int e = 0; e < 16; ++e) {
            int i = base + e * 256;
            if (i < NQ_) wqb[i] = f2bf(wq[i]);
            else if (i < NQ_ + NO_) wob[i - NQ_] = f2bf(wo[i - NQ_]);
            else {
                int j = i - (NQ_ + NO_);          // < 4096 by construction
                int m = j >> 5;
                relb[j] = (m < 127) ? f2bf(rel_emb[j]) : (unsigned short)0;
            }
        }
        return;
    }
    int virt = (bid & 7) * 96 + (bid >> 3);
    int n = virt / 12, r = virt % 12, cg = r >> 1, ih = r & 1;
    __shared__ unsigned short tile[800][40];   // 64000 B
    int tid = threadIdx.x;
    {
        int cc = tid >> 3, part = tid & 7;     // cc 0..31, 100 elems each
        const float4* src = (const float4*)(x + ((size_t)n * C_ + cg * 32 + cc) * 1600
                                              + ih * 800 + part * 100);
#pragma unroll
        for (int u = 0; u < 25; ++u) {
            float4 f = src[u];
            int i = part * 100 + u * 4;
            tile[i + 0][cc] = f2bf(f.x);
            tile[i + 1][cc] = f2bf(f.y);
            tile[i + 2][cc] = f2bf(f.z);
            tile[i + 3][cc] = f2bf(f.w);
        }
    }
    __syncthreads();
    for (int i = tid; i < 800; i += 256) {
        int gi = ih * 800 + i;
        int t = (gi * 5243) >> 17;             // gi/25 (exact for gi<1600)
        int v = gi - t * 25;
        unsigned short* dst = xt + (((size_t)(n * V_ + v) * T_) + t) * C_ + cg * 32;
        const s16x8* srow = (const s16x8*)&tile[i][0];
        ((s16x8*)dst)[0] = srow[0];
        ((s16x8*)dst)[1] = srow[1];
        ((s16x8*)dst)[2] = srow[2];
        ((s16x8*)dst)[3] = srow[3];
    }
}

// ---------------------------------------------------------------------------
// Kernel 2: FUSED (b, j) QKV GEMM + attention.  v5 deltas vs v4 (R17):
//   - per k-half, ALL 9 A-frags prefetched to regs before the MFMA block
//     (one latency window instead of 9 serial-dependent exposures)
//   - half-1 staging loads issued right after b1 (T14 async-stage: HBM
//     latency hides under half-0 compute); only ds_write remains at restage
// LDS layout and math identical to R17 (bit-identical, 40,960 B, 4 blk/CU).
// ---------------------------------------------------------------------------
__global__ __launch_bounds__(256, 4) void k_qa(const unsigned short* __restrict__ Wb,
                                               const float* __restrict__ bqkv,
                                               const unsigned short* __restrict__ xt,
                                               const unsigned short* __restrict__ relb,
                                               unsigned short* __restrict__ aT) {
    int virt = (blockIdx.x & 7) * 600 + (blockIdx.x >> 3);   // 4800 = 8*600
    int b = virt / 3, j = virt % 3;

    __shared__ __align__(16) unsigned short U[20480];        // 40,960 B
    unsigned short* xts  = U;            // [64][104] per k-half
    unsigned short* relw = U;            // wave*1408 + row*88 + col (half bits)
    unsigned short* wls  = U;            // wave*1408 + row*72 + col (aliases relw)
    unsigned short* qt   = U + 6656;     // [2][64][36]; ao aliases this
    unsigned short* ao   = U + 6656;
    unsigned short* kt   = U + 11264;    // [2][64][36]
    unsigned short* vsm  = U + 15872;    // [2][32][72]

    int tid = threadIdx.x;
    int wave = tid >> 6, lane = tid & 63;
    int lr = lane & 15, lg = lane >> 4;
    int w1 = wave & 1;
    int hh = wave >> 1;                  // local head of this wave
    int dh = w1 * 16;                    // d-base within head

    const unsigned short* xb = xt + (size_t)b * T_ * C_;
    int ts = tid >> 2, q4 = tid & 3;     // staging coords
    s16x8* dstx = (s16x8*)&xts[ts * 104 + q4 * 24];
    const unsigned short* wbase = Wb + (size_t)(j * 64 + wave * 16 + lr) * C_ + lg * 8;
    const size_t WPH = (size_t)3 * 64 * C_;   // phase stride in W rows

    f32x4 acc3[3][4];
#pragma unroll
    for (int p = 0; p < 3; ++p)
#pragma unroll
        for (int nt = 0; nt < 4; ++nt) acc3[p][nt] = (f32x4){0.f, 0.f, 0.f, 0.f};

    // ---- stage half 0 ----
    {
        const s16x8* src = (const s16x8*)(xb + (size_t)ts * C_ + q4 * 24);
        dstx[0] = src[0]; dstx[1] = src[1]; dstx[2] = src[2];
    }
    __syncthreads();                           // b1: half-0 staged

    // issue half-1 staging loads NOW (latency hides under half-0 compute)
    s16x8 st1_0, st1_1, st1_2;
    {
        const s16x8* src = (const s16x8*)(xb + (size_t)ts * C_ + 96 + q4 * 24);
        st1_0 = src[0]; st1_1 = src[1]; st1_2 = src[2];
    }

    // ---- half 0: prefetch 9 A-frags, then 36 MFMAs ----
    s16x8 af[9];
#pragma unroll
    for (int p = 0; p < 3; ++p)
#pragma unroll
        for (int ks = 0; ks < 3; ++ks)
            af[p * 3 + ks] = *(const s16x8*)(wbase + p * WPH + ks * 32);
#pragma unroll
    for (int p = 0; p < 3; ++p)
#pragma unroll
        for (int ks = 0; ks < 3; ++ks) {
            s16x8 a = af[p * 3 + ks];
#pragma unroll
            for (int nt = 0; nt < 4; ++nt) {
                s16x8 bfv = *(const s16x8*)&xts[(nt * 16 + lr) * 104 + ks * 32 + lg * 8];
                acc3[p][nt] = __builtin_amdgcn_mfma_f32_16x16x32_bf16(a, bfv, acc3[p][nt], 0, 0, 0);
            }
        }
    __syncthreads();                           // half-0 reads done

    // prefetch half-1 A-frags (latency hides under ds_write + barrier)
#pragma unroll
    for (int p = 0; p < 3; ++p)
#pragma unroll
        for (int ks = 0; ks < 3; ++ks)
            af[p * 3 + ks] = *(const s16x8*)(wbase + p * WPH + 96 + ks * 32);

    // write half-1 stage
    dstx[0] = st1_0; dstx[1] = st1_1; dstx[2] = st1_2;
    __syncthreads();                           // half-1 staged

#pragma unroll
    for (int p = 0; p < 3; ++p)
#pragma unroll
        for (int ks = 0; ks < 3; ++ks) {
            s16x8 a = af[p * 3 + ks];
#pragma unroll
            for (int nt = 0; nt < 4; ++nt) {
                s16x8 bfv = *(const s16x8*)&xts[(nt * 16 + lr) * 104 + ks * 32 + lg * 8];
                acc3[p][nt] = __builtin_amdgcn_mfma_f32_16x16x32_bf16(a, bfv, acc3[p][nt], 0, 0, 0);
            }
        }
    __syncthreads();                           // half-1 reads done (alias safe)

    // ---- epilogues: qt / kt / vsm ----
#pragma unroll
    for (int p = 0; p < 3; ++p) {
        int mo = p * 3 + j;
        if (p < 2) {
            unsigned short* dst = (p == 0 ? qt : kt);
#pragma unroll
            for (int nt = 0; nt < 4; ++nt) {
                s16x4 pk;
#pragma unroll
                for (int r2 = 0; r2 < 4; ++r2)
                    pk[r2] = (short)f2bf(acc3[p][nt][r2] +
                                         bqkv[mo * 64 + wave * 16 + lg * 4 + r2]);
                *(s16x4*)&dst[hh * 2304 + (nt * 16 + lr) * 36 + dh + lg * 4] = pk;
            }
        } else {
#pragma unroll
            for (int nt = 0; nt < 4; ++nt)
#pragma unroll
                for (int r2 = 0; r2 < 4; ++r2) {
                    int d = dh + lg * 4 + r2;
                    vsm[hh * 2304 + d * 72 + nt * 16 + lr] =
                        f2bf(acc3[p][nt][r2] + bqkv[mo * 64 + wave * 16 + lg * 4 + r2]);
                }
        }
    }
    // rel window union for both passes (6 tiles; pass r uses rfr6[1-r+ti])
    s16x8 rfr6[6];
#pragma unroll
    for (int ti = 0; ti < 6; ++ti) {
        int m = (2 - 2 * w1 + ti) * 16 + lr;
        rfr6[ti] = *(const s16x8*)(relb + m * 32 + lg * 8);
    }
    __syncthreads();                           // qt/kt/vsm complete; xts dead

    // ---- attention: 2 wave-local passes (R15 body) ----
#pragma unroll
    for (int r = 0; r < 2; ++r) {
        int strip = 2 * w1 + r;
        int t0s = strip * 16;

        int qoff = hh * 2304 + (t0s + lr) * 36 + lg * 8;
        s16x4 qlo = *(const s16x4*)&qt[qoff];
        s16x4 qhi = *(const s16x4*)&qt[qoff + 4];
        s16x8 afq = __builtin_shufflevector(qlo, qhi, 0, 1, 2, 3, 4, 5, 6, 7);

        f32x4 accS[4];
#pragma unroll
        for (int nt = 0; nt < 4; ++nt) {
            int koff = hh * 2304 + (nt * 16 + lr) * 36 + lg * 8;
            s16x4 klo = *(const s16x4*)&kt[koff];
            s16x4 khi = *(const s16x4*)&kt[koff + 4];
            s16x8 bk = __builtin_shufflevector(klo, khi, 0, 1, 2, 3, 4, 5, 6, 7);
            f32x4 z = (f32x4){0.f, 0.f, 0.f, 0.f};
            accS[nt] = __builtin_amdgcn_mfma_f32_16x16x32_bf16(afq, bk, z, 0, 0, 0);
        }
#pragma unroll
        for (int ti = 0; ti < 5; ++ti) {
            f32x4 z = (f32x4){0.f, 0.f, 0.f, 0.f};
            f32x4 rr = __builtin_amdgcn_mfma_f32_16x16x32_bf16(afq, rfr6[1 - r + ti], z, 0, 0, 0);
#pragma unroll
            for (int r2 = 0; r2 < 4; ++r2)
                relw[wave * 1408 + (lg * 4 + r2) * 88 + ti * 16 + lr] =
                    __half_as_ushort(__float2half(rr[r2]));
        }
        // softmax (wave-local; relw wave-private)
        float vals[4][4], mx[4], inv[4];
#pragma unroll
        for (int r2 = 0; r2 < 4; ++r2) {
            int row = lg * 4 + r2;
            float m0 = -1e30f;
#pragma unroll
            for (int nt = 0; nt < 4; ++nt) {
                int s = nt * 16 + lr;
                float v = accS[nt][r2] + __half2float(__ushort_as_half(
                              relw[wave * 1408 + row * 88 + (s - row + 15)]));
                vals[nt][r2] = v;
                m0 = fmaxf(m0, v);
            }
            m0 = fmaxf(m0, __shfl_xor(m0, 1));
            m0 = fmaxf(m0, __shfl_xor(m0, 2));
            m0 = fmaxf(m0, __shfl_xor(m0, 4));
            m0 = fmaxf(m0, __shfl_xor(m0, 8));
            mx[r2] = m0;
        }
#pragma unroll
        for (int r2 = 0; r2 < 4; ++r2) {
            float s0 = 0.f;
#pragma unroll
            for (int nt = 0; nt < 4; ++nt) {
                float e = __expf(vals[nt][r2] - mx[r2]);
                vals[nt][r2] = e;
                s0 += e;
            }
            s0 += __shfl_xor(s0, 1);
            s0 += __shfl_xor(s0, 2);
            s0 += __shfl_xor(s0, 4);
            s0 += __shfl_xor(s0, 8);
            inv[r2] = 1.0f / s0;
        }
        // wls writes alias relw: all relw reads above complete (same wave,
        // program order; DS ops wave-ordered; same-type may-alias)
#pragma unroll
        for (int r2 = 0; r2 < 4; ++r2) {
            int row = lg * 4 + r2;
#pragma unroll
            for (int nt = 0; nt < 4; ++nt)
                wls[wave * 1408 + row * 72 + nt * 16 + lr] =
                    f2bf(vals[nt][r2] * inv[r2]);
        }
        // PV (wls wave-private)
        f32x4 accO[2];
        accO[0] = (f32x4){0.f, 0.f, 0.f, 0.f};
        accO[1] = (f32x4){0.f, 0.f, 0.f, 0.f};
#pragma unroll
        for (int ks = 0; ks < 2; ++ks) {
            s16x8 pa = *(const s16x8*)&wls[wave * 1408 + lr * 72 + ks * 32 + lg * 8];
#pragma unroll
            for (int nt = 0; nt < 2; ++nt) {
                s16x8 bv = *(const s16x8*)&vsm[hh * 2304 + (nt * 16 + lr) * 72 +
                                               ks * 32 + lg * 8];
                accO[nt] = __builtin_amdgcn_mfma_f32_16x16x32_bf16(pa, bv, accO[nt], 0, 0, 0);
            }
        }
        // ao overwrites qt[strip rows] — afq for this strip already consumed;
        // other wave of head hh owns disjoint strips
#pragma unroll
        for (int nt = 0; nt < 2; ++nt)
#pragma unroll
            for (int r2 = 0; r2 < 4; ++r2)
                ao[hh * 2304 + (t0s + lg * 4 + r2) * 36 + nt * 16 + lr] =
                    f2bf(accO[nt][r2]);
    }
    __syncthreads();                           // ao complete

    // scrambled write for both heads: aT[b][tout][(2j+hh)*32+qr] = ao[hh][tAo][dA]
    unsigned short* dstb = aT + (size_t)b * T_ * C_ + 2 * j * D_;
#pragma unroll
    for (int it = 0; it < 16; ++it) {
        int idx = it * 256 + tid;              // 0..4095
        int hh2 = idx >> 11;
        int e = idx & 2047;
        int qr = e & 31, tout = e >> 5;
        int ii = tout & 31;
        int jj = 2 * qr + (tout >> 5);
        int tAo = 2 * ii + (jj >> 5);
        int dA = jj & 31;
        dstb[(size_t)tout * C_ + hh2 * D_ + qr] = ao[hh2 * 2304 + tAo * 36 + dA];
    }
}

// ---------------------------------------------------------------------------
// Kernel 3: out GEMM (bf16 MFMA), writes final (N,C,T,V) fp32. XCD-swizzled.
// (round-9 scatter epilogue)
// ---------------------------------------------------------------------------
__global__ __launch_bounds__(256) void k_out(const unsigned short* __restrict__ Wb,
                                             const float* __restrict__ bias,
                                             const unsigned short* __restrict__ aT,
                                             float* __restrict__ out) {
    int virt = (blockIdx.x & 7) * (768 / 8) + (blockIdx.x >> 3);
    int n = virt / 12, r = virt % 12, mo = r >> 2, tc = r & 3;
    __shared__ unsigned short Bs[400][40];     // [col][k], 32KB
    int tid = threadIdx.x;
    int wave = tid >> 6, lane = tid & 63;
    int lr = lane & 15, lg = lane >> 4;

    f32x4 acc[25];
#pragma unroll
    for (int j = 0; j < 25; ++j) acc[j] = (f32x4){0.f, 0.f, 0.f, 0.f};

    const unsigned short* arow = Wb + (size_t)(mo * 64 + wave * 16 + lr) * C_ + lg * 8;

    for (int k0 = 0; k0 < C_; k0 += 32) {
        __syncthreads();
        for (int col = tid; col < 400; col += 256) {
            int tl = (col * 41) >> 10;         // col/25 (exact for col<624)
            int v = col - tl * 25;
            const s16x8* src = (const s16x8*)(aT +
                ((size_t)(n * V_ + v) * T_ + tc * 16 + tl) * C_ + k0);
            s16x8* dst = (s16x8*)&Bs[col][0];
            dst[0] = src[0]; dst[1] = src[1]; dst[2] = src[2]; dst[3] = src[3];
        }
        __syncthreads();
        s16x8 a = *(const s16x8*)(arow + k0);
#pragma unroll
        for (int j = 0; j < 25; ++j) {
            s16x8 bf = *(const s16x8*)&Bs[j * 16 + lr][lg * 8];
            acc[j] = __builtin_amdgcn_mfma_f32_16x16x32_bf16(a, bf, acc[j], 0, 0, 0);
        }
    }
#pragma unroll
    for (int j = 0; j < 25; ++j) {
        int c = j * 16 + lr;
        int tl = (c * 41) >> 10;
        int v = c - tl * 25;
        int t = tc * 16 + tl;
#pragma unroll
        for (int r2 = 0; r2 < 4; ++r2) {
            int o = mo * 64 + wave * 16 + lg * 4 + r2;
            out[(((size_t)n * C_ + o) * T_ + t) * V_ + v] = acc[j][r2] + bias[o];
        }
    }
}

// ---------------------------------------------------------------------------
extern "C" void kernel_launch(void* const* d_in, const int* in_sizes, int n_in,
                              void* d_out, int out_size, void* d_ws, size_t ws_size,
                              hipStream_t stream) {
    const float* x       = (const float*)d_in[0];
    const float* w_qkv   = (const float*)d_in[1];
    const float* b_qkv   = (const float*)d_in[2];
    const float* w_out   = (const float*)d_in[3];
    const float* b_out   = (const float*)d_in[4];
    const float* rel_emb = (const float*)d_in[5];
    float* out = (float*)d_out;

    // workspace (ushorts): xt | aT | wqb | wob | relb
    const size_t PLANE = (size_t)B_ * T_ * C_;   // 19,660,800
    unsigned short* xt   = (unsigned short*)d_ws;
    unsigned short* aTb  = xt + PLANE;
    unsigned short* wqb  = aTb + PLANE;
    unsigned short* wob  = wqb + (size_t)NQ_;
    unsigned short* relb = wob + (size_t)NO_;

    k_xw<<<805, 256, 0, stream>>>(x, w_qkv, w_out, rel_emb, xt, wqb, wob, relb);
    k_qa<<<4800, 256, 0, stream>>>(wqb, b_qkv, xt, relb, aTb);
    k_out<<<768, 256, 0, stream>>>(wob, b_out, aTb, out);
}

// Round 19
// 140.995 us; speedup vs baseline: 2.1427x; 1.0509x over previous
//
#include <hip/hip_runtime.h>
#include <hip/hip_bf16.h>
#include <hip/hip_fp16.h>
#include <stdint.h>

// Problem dims (fixed): N=64, C=192, T=64, V=25, H=6, d=32, B=N*V=1600
#define N_ 64
#define C_ 192
#define T_ 64
#define V_ 25
#define H_ 6
#define D_ 32
#define B_ 1600
#define NQ_ (3 * C_ * C_)   // 110592
#define NO_ (C_ * C_)       // 36864

typedef __attribute__((ext_vector_type(8))) short s16x8;
typedef __attribute__((ext_vector_type(4))) short s16x4;
typedef __attribute__((ext_vector_type(4))) float f32x4;

__device__ __forceinline__ unsigned short f2bf(float f) {
    union { float f; uint32_t u; } v; v.f = f;
    uint32_t r = v.u + 0x7FFFu + ((v.u >> 16) & 1u);   // RNE
    return (unsigned short)(r >> 16);
}

// ---------------------------------------------------------------------------
// Kernel 1: merged  (a) x (N,C,T,V) fp32 -> xt[(n*V+v)][t][c] bf16  [768 blk]
//                   (b) weights+rel -> bf16                          [37 blk]
// ---------------------------------------------------------------------------
__global__ __launch_bounds__(256) void k_xw(const float* __restrict__ x,
                                            const float* __restrict__ wq,
                                            const float* __restrict__ wo,
                                            const float* __restrict__ rel_emb,
                                            unsigned short* __restrict__ xt,
                                            unsigned short* __restrict__ wqb,
                                            unsigned short* __restrict__ wob,
                                            unsigned short* __restrict__ relb) {
    int bid = blockIdx.x;
    if (bid >= 768) {
        int base = (bid - 768) * 4096 + threadIdx.x;
#pragma unroll
        for (int e = 0; e < 16; ++e) {
            int i = base + e * 256;
            if (i < NQ_) wqb[i] = f2bf(wq[i]);
            else if (i < NQ_ + NO_) wob[i - NQ_] = f2bf(wo[i - NQ_]);
            else {
                int j = i - (NQ_ + NO_);          // < 4096 by construction
                int m = j >> 5;
                relb[j] = (m < 127) ? f2bf(rel_emb[j]) : (unsigned short)0;
            }
        }
        return;
    }
    int virt = (bid & 7) * 96 + (bid >> 3);
    int n = virt / 12, r = virt % 12, cg = r >> 1, ih = r & 1;
    __shared__ unsigned short tile[800][40];   // 64000 B
    int tid = threadIdx.x;
    {
        int cc = tid >> 3, part = tid & 7;     // cc 0..31, 100 elems each
        const float4* src = (const float4*)(x + ((size_t)n * C_ + cg * 32 + cc) * 1600
                                              + ih * 800 + part * 100);
#pragma unroll
        for (int u = 0; u < 25; ++u) {
            float4 f = src[u];
            int i = part * 100 + u * 4;
            tile[i + 0][cc] = f2bf(f.x);
            tile[i + 1][cc] = f2bf(f.y);
            tile[i + 2][cc] = f2bf(f.z);
            tile[i + 3][cc] = f2bf(f.w);
        }
    }
    __syncthreads();
    for (int i = tid; i < 800; i += 256) {
        int gi = ih * 800 + i;
        int t = (gi * 5243) >> 17;             // gi/25 (exact for gi<1600)
        int v = gi - t * 25;
        unsigned short* dst = xt + (((size_t)(n * V_ + v) * T_) + t) * C_ + cg * 32;
        const s16x8* srow = (const s16x8*)&tile[i][0];
        ((s16x8*)dst)[0] = srow[0];
        ((s16x8*)dst)[1] = srow[1];
        ((s16x8*)dst)[2] = srow[2];
        ((s16x8*)dst)[3] = srow[3];
    }
}

// ---------------------------------------------------------------------------
// Kernel 2: FUSED (b, j) QKV GEMM + attention.  v6 deltas vs v5 (R18):
//   - GEMM loop ks-OUTER with B-frag hoisting: 4 B-frags loaded once per ks,
//     reused across all 3 phases -> 24 (was 72) ds_read_b128 per wave.
//     Per-accumulator k-order unchanged (bit-identical).
//   - relw stride 88 -> 90 ushorts (odd dword stride spreads lg-groups
//     across banks; was the main SQ_LDS_BANK_CONFLICT source).
// LDS 40,960 B, 4 blocks/CU (unchanged).
// ---------------------------------------------------------------------------
__global__ __launch_bounds__(256, 4) void k_qa(const unsigned short* __restrict__ Wb,
                                               const float* __restrict__ bqkv,
                                               const unsigned short* __restrict__ xt,
                                               const unsigned short* __restrict__ relb,
                                               unsigned short* __restrict__ aT) {
    int virt = (blockIdx.x & 7) * 600 + (blockIdx.x >> 3);   // 4800 = 8*600
    int b = virt / 3, j = virt % 3;

    __shared__ __align__(16) unsigned short U[20480];        // 40,960 B
    unsigned short* xts  = U;            // [64][104] per k-half
    unsigned short* relw = U;            // wave*1440 + row*90 + col (half bits)
    unsigned short* wls  = U;            // wave*1440 + row*72 + col (aliases relw)
    unsigned short* qt   = U + 6656;     // [2][64][36]; ao aliases this
    unsigned short* ao   = U + 6656;
    unsigned short* kt   = U + 11264;    // [2][64][36]
    unsigned short* vsm  = U + 15872;    // [2][32][72]

    int tid = threadIdx.x;
    int wave = tid >> 6, lane = tid & 63;
    int lr = lane & 15, lg = lane >> 4;
    int w1 = wave & 1;
    int hh = wave >> 1;                  // local head of this wave
    int dh = w1 * 16;                    // d-base within head

    const unsigned short* xb = xt + (size_t)b * T_ * C_;
    int ts = tid >> 2, q4 = tid & 3;     // staging coords
    s16x8* dstx = (s16x8*)&xts[ts * 104 + q4 * 24];
    const unsigned short* wbase = Wb + (size_t)(j * 64 + wave * 16 + lr) * C_ + lg * 8;
    const size_t WPH = (size_t)3 * 64 * C_;   // phase stride in W rows

    f32x4 acc3[3][4];
#pragma unroll
    for (int p = 0; p < 3; ++p)
#pragma unroll
        for (int nt = 0; nt < 4; ++nt) acc3[p][nt] = (f32x4){0.f, 0.f, 0.f, 0.f};

    // ---- stage half 0 ----
    {
        const s16x8* src = (const s16x8*)(xb + (size_t)ts * C_ + q4 * 24);
        dstx[0] = src[0]; dstx[1] = src[1]; dstx[2] = src[2];
    }
    __syncthreads();                           // b1: half-0 staged

    // issue half-1 staging loads NOW (latency hides under half-0 compute)
    s16x8 st1_0, st1_1, st1_2;
    {
        const s16x8* src = (const s16x8*)(xb + (size_t)ts * C_ + 96 + q4 * 24);
        st1_0 = src[0]; st1_1 = src[1]; st1_2 = src[2];
    }

    // ---- half 0: prefetch 9 A-frags; ks-outer MFMAs with B-frag reuse ----
    s16x8 af[9];
#pragma unroll
    for (int p = 0; p < 3; ++p)
#pragma unroll
        for (int ks = 0; ks < 3; ++ks)
            af[p * 3 + ks] = *(const s16x8*)(wbase + p * WPH + ks * 32);
#pragma unroll
    for (int ks = 0; ks < 3; ++ks) {
        s16x8 bfv[4];
#pragma unroll
        for (int nt = 0; nt < 4; ++nt)
            bfv[nt] = *(const s16x8*)&xts[(nt * 16 + lr) * 104 + ks * 32 + lg * 8];
#pragma unroll
        for (int p = 0; p < 3; ++p)
#pragma unroll
            for (int nt = 0; nt < 4; ++nt)
                acc3[p][nt] = __builtin_amdgcn_mfma_f32_16x16x32_bf16(af[p * 3 + ks], bfv[nt], acc3[p][nt], 0, 0, 0);
    }
    __syncthreads();                           // half-0 reads done

    // prefetch half-1 A-frags (latency hides under ds_write + barrier)
#pragma unroll
    for (int p = 0; p < 3; ++p)
#pragma unroll
        for (int ks = 0; ks < 3; ++ks)
            af[p * 3 + ks] = *(const s16x8*)(wbase + p * WPH + 96 + ks * 32);

    // write half-1 stage
    dstx[0] = st1_0; dstx[1] = st1_1; dstx[2] = st1_2;
    __syncthreads();                           // half-1 staged

#pragma unroll
    for (int ks = 0; ks < 3; ++ks) {
        s16x8 bfv[4];
#pragma unroll
        for (int nt = 0; nt < 4; ++nt)
            bfv[nt] = *(const s16x8*)&xts[(nt * 16 + lr) * 104 + ks * 32 + lg * 8];
#pragma unroll
        for (int p = 0; p < 3; ++p)
#pragma unroll
            for (int nt = 0; nt < 4; ++nt)
                acc3[p][nt] = __builtin_amdgcn_mfma_f32_16x16x32_bf16(af[p * 3 + ks], bfv[nt], acc3[p][nt], 0, 0, 0);
    }
    __syncthreads();                           // half-1 reads done (alias safe)

    // ---- epilogues: qt / kt / vsm ----
#pragma unroll
    for (int p = 0; p < 3; ++p) {
        int mo = p * 3 + j;
        if (p < 2) {
            unsigned short* dst = (p == 0 ? qt : kt);
#pragma unroll
            for (int nt = 0; nt < 4; ++nt) {
                s16x4 pk;
#pragma unroll
                for (int r2 = 0; r2 < 4; ++r2)
                    pk[r2] = (short)f2bf(acc3[p][nt][r2] +
                                         bqkv[mo * 64 + wave * 16 + lg * 4 + r2]);
                *(s16x4*)&dst[hh * 2304 + (nt * 16 + lr) * 36 + dh + lg * 4] = pk;
            }
        } else {
#pragma unroll
            for (int nt = 0; nt < 4; ++nt)
#pragma unroll
                for (int r2 = 0; r2 < 4; ++r2) {
                    int d = dh + lg * 4 + r2;
                    vsm[hh * 2304 + d * 72 + nt * 16 + lr] =
                        f2bf(acc3[p][nt][r2] + bqkv[mo * 64 + wave * 16 + lg * 4 + r2]);
                }
        }
    }
    // rel window union for both passes (6 tiles; pass r uses rfr6[1-r+ti])
    s16x8 rfr6[6];
#pragma unroll
    for (int ti = 0; ti < 6; ++ti) {
        int m = (2 - 2 * w1 + ti) * 16 + lr;
        rfr6[ti] = *(const s16x8*)(relb + m * 32 + lg * 8);
    }
    __syncthreads();                           // qt/kt/vsm complete; xts dead

    // ---- attention: 2 wave-local passes ----
#pragma unroll
    for (int r = 0; r < 2; ++r) {
        int strip = 2 * w1 + r;
        int t0s = strip * 16;

        int qoff = hh * 2304 + (t0s + lr) * 36 + lg * 8;
        s16x4 qlo = *(const s16x4*)&qt[qoff];
        s16x4 qhi = *(const s16x4*)&qt[qoff + 4];
        s16x8 afq = __builtin_shufflevector(qlo, qhi, 0, 1, 2, 3, 4, 5, 6, 7);

        f32x4 accS[4];
#pragma unroll
        for (int nt = 0; nt < 4; ++nt) {
            int koff = hh * 2304 + (nt * 16 + lr) * 36 + lg * 8;
            s16x4 klo = *(const s16x4*)&kt[koff];
            s16x4 khi = *(const s16x4*)&kt[koff + 4];
            s16x8 bk = __builtin_shufflevector(klo, khi, 0, 1, 2, 3, 4, 5, 6, 7);
            f32x4 z = (f32x4){0.f, 0.f, 0.f, 0.f};
            accS[nt] = __builtin_amdgcn_mfma_f32_16x16x32_bf16(afq, bk, z, 0, 0, 0);
        }
#pragma unroll
        for (int ti = 0; ti < 5; ++ti) {
            f32x4 z = (f32x4){0.f, 0.f, 0.f, 0.f};
            f32x4 rr = __builtin_amdgcn_mfma_f32_16x16x32_bf16(afq, rfr6[1 - r + ti], z, 0, 0, 0);
#pragma unroll
            for (int r2 = 0; r2 < 4; ++r2)
                relw[wave * 1440 + (lg * 4 + r2) * 90 + ti * 16 + lr] =
                    __half_as_ushort(__float2half(rr[r2]));
        }
        // softmax (wave-local; relw wave-private)
        float vals[4][4], mx[4], inv[4];
#pragma unroll
        for (int r2 = 0; r2 < 4; ++r2) {
            int row = lg * 4 + r2;
            float m0 = -1e30f;
#pragma unroll
            for (int nt = 0; nt < 4; ++nt) {
                int s = nt * 16 + lr;
                float v = accS[nt][r2] + __half2float(__ushort_as_half(
                              relw[wave * 1440 + row * 90 + (s - row + 15)]));
                vals[nt][r2] = v;
                m0 = fmaxf(m0, v);
            }
            m0 = fmaxf(m0, __shfl_xor(m0, 1));
            m0 = fmaxf(m0, __shfl_xor(m0, 2));
            m0 = fmaxf(m0, __shfl_xor(m0, 4));
            m0 = fmaxf(m0, __shfl_xor(m0, 8));
            mx[r2] = m0;
        }
#pragma unroll
        for (int r2 = 0; r2 < 4; ++r2) {
            float s0 = 0.f;
#pragma unroll
            for (int nt = 0; nt < 4; ++nt) {
                float e = __expf(vals[nt][r2] - mx[r2]);
                vals[nt][r2] = e;
                s0 += e;
            }
            s0 += __shfl_xor(s0, 1);
            s0 += __shfl_xor(s0, 2);
            s0 += __shfl_xor(s0, 4);
            s0 += __shfl_xor(s0, 8);
            inv[r2] = 1.0f / s0;
        }
        // wls writes alias relw: all relw reads above complete (same wave,
        // program order; DS ops wave-ordered; same-type may-alias)
#pragma unroll
        for (int r2 = 0; r2 < 4; ++r2) {
            int row = lg * 4 + r2;
#pragma unroll
            for (int nt = 0; nt < 4; ++nt)
                wls[wave * 1440 + row * 72 + nt * 16 + lr] =
                    f2bf(vals[nt][r2] * inv[r2]);
        }
        // PV (wls wave-private)
        f32x4 accO[2];
        accO[0] = (f32x4){0.f, 0.f, 0.f, 0.f};
        accO[1] = (f32x4){0.f, 0.f, 0.f, 0.f};
#pragma unroll
        for (int ks = 0; ks < 2; ++ks) {
            s16x8 pa = *(const s16x8*)&wls[wave * 1440 + lr * 72 + ks * 32 + lg * 8];
#pragma unroll
            for (int nt = 0; nt < 2; ++nt) {
                s16x8 bv = *(const s16x8*)&vsm[hh * 2304 + (nt * 16 + lr) * 72 +
                                               ks * 32 + lg * 8];
                accO[nt] = __builtin_amdgcn_mfma_f32_16x16x32_bf16(pa, bv, accO[nt], 0, 0, 0);
            }
        }
        // ao overwrites qt[strip rows] — afq for this strip already consumed;
        // other wave of head hh owns disjoint strips
#pragma unroll
        for (int nt = 0; nt < 2; ++nt)
#pragma unroll
            for (int r2 = 0; r2 < 4; ++r2)
                ao[hh * 2304 + (t0s + lg * 4 + r2) * 36 + nt * 16 + lr] =
                    f2bf(accO[nt][r2]);
    }
    __syncthreads();                           // ao complete

    // scrambled write for both heads: aT[b][tout][(2j+hh)*32+qr] = ao[hh][tAo][dA]
    unsigned short* dstb = aT + (size_t)b * T_ * C_ + 2 * j * D_;
#pragma unroll
    for (int it = 0; it < 16; ++it) {
        int idx = it * 256 + tid;              // 0..4095
        int hh2 = idx >> 11;
        int e = idx & 2047;
        int qr = e & 31, tout = e >> 5;
        int ii = tout & 31;
        int jj = 2 * qr + (tout >> 5);
        int tAo = 2 * ii + (jj >> 5);
        int dA = jj & 31;
        dstb[(size_t)tout * C_ + hh2 * D_ + qr] = ao[hh2 * 2304 + tAo * 36 + dA];
    }
}

// ---------------------------------------------------------------------------
// Kernel 3: out GEMM (bf16 MFMA), writes final (N,C,T,V) fp32. XCD-swizzled.
// (round-9 scatter epilogue)
// ---------------------------------------------------------------------------
__global__ __launch_bounds__(256) void k_out(const unsigned short* __restrict__ Wb,
                                             const float* __restrict__ bias,
                                             const unsigned short* __restrict__ aT,
                                             float* __restrict__ out) {
    int virt = (blockIdx.x & 7) * (768 / 8) + (blockIdx.x >> 3);
    int n = virt / 12, r = virt % 12, mo = r >> 2, tc = r & 3;
    __shared__ unsigned short Bs[400][40];     // [col][k], 32KB
    int tid = threadIdx.x;
    int wave = tid >> 6, lane = tid & 63;
    int lr = lane & 15, lg = lane >> 4;

    f32x4 acc[25];
#pragma unroll
    for (int j = 0; j < 25; ++j) acc[j] = (f32x4){0.f, 0.f, 0.f, 0.f};

    const unsigned short* arow = Wb + (size_t)(mo * 64 + wave * 16 + lr) * C_ + lg * 8;

    for (int k0 = 0; k0 < C_; k0 += 32) {
        __syncthreads();
        for (int col = tid; col < 400; col += 256) {
            int tl = (col * 41) >> 10;         // col/25 (exact for col<624)
            int v = col - tl * 25;
            const s16x8* src = (const s16x8*)(aT +
                ((size_t)(n * V_ + v) * T_ + tc * 16 + tl) * C_ + k0);
            s16x8* dst = (s16x8*)&Bs[col][0];
            dst[0] = src[0]; dst[1] = src[1]; dst[2] = src[2]; dst[3] = src[3];
        }
        __syncthreads();
        s16x8 a = *(const s16x8*)(arow + k0);
#pragma unroll
        for (int j = 0; j < 25; ++j) {
            s16x8 bf = *(const s16x8*)&Bs[j * 16 + lr][lg * 8];
            acc[j] = __builtin_amdgcn_mfma_f32_16x16x32_bf16(a, bf, acc[j], 0, 0, 0);
        }
    }
#pragma unroll
    for (int j = 0; j < 25; ++j) {
        int c = j * 16 + lr;
        int tl = (c * 41) >> 10;
        int v = c - tl * 25;
        int t = tc * 16 + tl;
#pragma unroll
        for (int r2 = 0; r2 < 4; ++r2) {
            int o = mo * 64 + wave * 16 + lg * 4 + r2;
            out[(((size_t)n * C_ + o) * T_ + t) * V_ + v] = acc[j][r2] + bias[o];
        }
    }
}

// ---------------------------------------------------------------------------
extern "C" void kernel_launch(void* const* d_in, const int* in_sizes, int n_in,
                              void* d_out, int out_size, void* d_ws, size_t ws_size,
                              hipStream_t stream) {
    const float* x       = (const float*)d_in[0];
    const float* w_qkv   = (const float*)d_in[1];
    const float* b_qkv   = (const float*)d_in[2];
    const float* w_out   = (const float*)d_in[3];
    const float* b_out   = (const float*)d_in[4];
    const float* rel_emb = (const float*)d_in[5];
    float* out = (float*)d_out;

    // workspace (ushorts): xt | aT | wqb | wob | relb
    const size_t PLANE = (size_t)B_ * T_ * C_;   // 19,660,800
    unsigned short* xt   = (unsigned short*)d_ws;
    unsigned short* aTb  = xt + PLANE;
    unsigned short* wqb  = aTb + PLANE;
    unsigned short* wob  = wqb + (size_t)NQ_;
    unsigned short* relb = wob + (size_t)NO_;

    k_xw<<<805, 256, 0, stream>>>(x, w_qkv, w_out, rel_emb, xt, wqb, wob, relb);
    k_qa<<<4800, 256, 0, stream>>>(wqb, b_qkv, xt, relb, aTb);
    k_out<<<768, 256, 0, stream>>>(wob, b_out, aTb, out);
}